// Round 6
// baseline (581.454 us; speedup 1.0000x reference)
//
#include <hip/hip_runtime.h>

#define DEVI __device__ __forceinline__

// ---------- helpers ----------
DEVI unsigned fkey(float f) {             // order-preserving float->uint key
  unsigned u = __float_as_uint(f);
  return u ^ ((u >> 31) ? 0xFFFFFFFFu : 0x80000000u);
}
DEVI float funkey(unsigned k) {
  unsigned b = (k & 0x80000000u) ? (k ^ 0x80000000u) : ~k;
  return __uint_as_float(b);
}
DEVI float f4get(const float4& v, int j) {
  return j == 0 ? v.x : j == 1 ? v.y : j == 2 ? v.z : v.w;
}

// ================= CSR build: bucketed counting sort by dst =================
constexpr int BSH = 9;                 // 512 nodes per bucket
constexpr int BNODES = 1 << BSH;
constexpr int PEPT = 16;               // partition: edges per thread
constexpr int PCHUNK = 256 * PEPT;     // 4096 edges per block

__global__ void k_binit(int* __restrict__ bcnt) {
  bcnt[threadIdx.x] = 0;
}

__global__ void k_bcount(const int* __restrict__ dst, int* __restrict__ bcnt,
                         int E, int NB) {
  __shared__ int lh[256];
  lh[threadIdx.x] = 0;
  __syncthreads();
  int stride = gridDim.x * 256;
  for (long i = (long)blockIdx.x * 256 + threadIdx.x; i < E; i += stride)
    atomicAdd(&lh[dst[i] >> BSH], 1);
  __syncthreads();
  if (threadIdx.x < NB && lh[threadIdx.x]) atomicAdd(&bcnt[threadIdx.x], lh[threadIdx.x]);
}

__global__ void k_bscan(const int* __restrict__ bcnt, int* __restrict__ bbase,
                        int* __restrict__ bcur, unsigned* __restrict__ scal, int NB) {
  __shared__ int s[256];
  int t = threadIdx.x;
  int v = (t < NB) ? bcnt[t] : 0;
  s[t] = v;
  __syncthreads();
  for (int o = 1; o < 256; o <<= 1) {
    int add = (t >= o) ? s[t - o] : 0;
    __syncthreads();
    s[t] += add;
    __syncthreads();
  }
  int excl = s[t] - v;
  if (t < NB) { bbase[t] = excl; bcur[t] = excl; }
  if (t == 0) { scal[0] = 0u; scal[1] = 0u; }
}

// pack = (dst&511)<<17 | src  (requires N <= 2^17)
__global__ __launch_bounds__(256)
void k_bpart(const int* __restrict__ src, const int* __restrict__ dst,
             int* __restrict__ bcur, unsigned* __restrict__ epart, int E, int NB) {
  __shared__ int lh[256];
  __shared__ int gbase[256];
  long base = (long)blockIdx.x * PCHUNK;
  lh[threadIdx.x] = 0;
  __syncthreads();
  int ed[PEPT]; int es[PEPT]; unsigned short lpos[PEPT];
#pragma unroll
  for (int j = 0; j < PEPT; j++) {
    long i = base + threadIdx.x + (long)j * 256;   // coalesced
    if (i < E) {
      int d = dst[i];
      es[j] = src[i];
      ed[j] = d;
      lpos[j] = (unsigned short)atomicAdd(&lh[d >> BSH], 1);
    } else {
      ed[j] = -1;
    }
  }
  __syncthreads();
  if (threadIdx.x < NB) {
    int c = lh[threadIdx.x];
    gbase[threadIdx.x] = c ? atomicAdd(&bcur[threadIdx.x], c) : 0;
  }
  __syncthreads();
#pragma unroll
  for (int j = 0; j < PEPT; j++) {
    int d = ed[j];
    if (d >= 0) {
      unsigned p = (unsigned)(gbase[d >> BSH] + (int)lpos[j]);
      epart[p] = ((unsigned)(d & (BNODES - 1)) << 17) | (unsigned)es[j];
    }
  }
}

// one block per bucket: per-node hist + scan -> deg/rowptr/dinv, scatter col
__global__ __launch_bounds__(256)
void k_fine(const unsigned* __restrict__ epart, const int* __restrict__ bbase,
            const int* __restrict__ bcnt, int* __restrict__ rowptr,
            int* __restrict__ deg, float* __restrict__ dinv,
            int* __restrict__ col, int N) {
  __shared__ int lh[BNODES];
  __shared__ int lexcl[BNODES];
  __shared__ int ssc[256];
  int b = blockIdx.x;
  int base = bbase[b], cnt = bcnt[b];
  int nlo = b << BSH;
  int t = threadIdx.x;
  lh[t] = 0; lh[t + 256] = 0;
  __syncthreads();
  for (int i = t; i < cnt; i += 256) {
    unsigned e = epart[base + i];
    atomicAdd(&lh[e >> 17], 1);
  }
  __syncthreads();
  int a0 = lh[2 * t], a1 = lh[2 * t + 1];
  ssc[t] = a0 + a1;
  __syncthreads();
  for (int o = 1; o < 256; o <<= 1) {
    int add = (t >= o) ? ssc[t - o] : 0;
    __syncthreads();
    ssc[t] += add;
    __syncthreads();
  }
  int excl = ssc[t] - (a0 + a1);
  lexcl[2 * t] = excl;
  lexcl[2 * t + 1] = excl + a0;
  __syncthreads();
#pragma unroll
  for (int k = 0; k < 2; k++) {
    int i = t + k * 256;
    int v = nlo + i;
    if (v < N) {
      int dgv = lh[i];
      deg[v] = dgv;
      rowptr[v] = base + lexcl[i];
      dinv[v] = rsqrtf((float)(dgv + 1));
    }
  }
  __syncthreads();
  lh[2 * t] = lexcl[2 * t];
  lh[2 * t + 1] = lexcl[2 * t + 1];
  __syncthreads();
  for (int i = t; i < cnt; i += 256) {
    unsigned e = epart[base + i];
    int p = atomicAdd(&lh[e >> 17], 1);
    col[base + p] = (int)(e & 0x1FFFFu);
  }
}

// ---------- tall-skinny fp32 GEMM: out = post(in[NxK] @ W[KxCOLS]) ----------
// ROWS x 8 micro-tile per thread: the 2 ds_read_b128 per k-step feed ROWS*8
// FMAs. ROWS=4 -> 1.0 FMA/LDS-byte (ROWS=1 was 0.25 -> LDS-BW-bound at 3.2 GB
// of W re-reads, 89 us in R5). k-loop unroll capped at 2 (R3: full unroll
// hoisted all loads -> 256 VGPR -> scratch spill).
template <int K, int KP, int COLS, int BT, int ROWS,
          bool BIAS, bool RELU, bool SCALE, bool DOMAX>
__launch_bounds__(BT)
__global__ void k_gemm(const float* __restrict__ in, const float* __restrict__ W,
                       const float* __restrict__ bias, const float* __restrict__ dinv,
                       float* __restrict__ out, int N, unsigned* __restrict__ gmax) {
  constexpr int CG = COLS / 8;        // col-groups of 8
  constexpr int RG = BT / CG;         // row-groups
  constexpr int RPB = RG * ROWS;      // rows per block
  __shared__ float Wl[KP * COLS];

  int cg = threadIdx.x % CG, rg = threadIdx.x / CG;
  int c0 = cg * 8;
  long r0 = (long)blockIdx.x * RPB + rg * ROWS;

  float acc[ROWS][8];
#pragma unroll
  for (int i = 0; i < ROWS; i++)
#pragma unroll
    for (int c = 0; c < 8; c++) acc[i][c] = 0.f;
  bool rv[ROWS];
#pragma unroll
  for (int i = 0; i < ROWS; i++) rv[i] = (r0 + i) < (long)N;

  const float* ip = in + r0 * K;
  for (int kp = 0; kp < K; kp += KP) {
    if (kp) __syncthreads();
    for (int i = threadIdx.x; i < KP * COLS; i += BT) Wl[i] = W[kp * COLS + i];
    __syncthreads();
#pragma unroll 2
    for (int k = 0; k < KP; k += 4) {
      float4 xv[ROWS];
#pragma unroll
      for (int i = 0; i < ROWS; i++)
        xv[i] = rv[i] ? *(const float4*)(ip + (long)i * K + kp + k)
                      : make_float4(0.f, 0.f, 0.f, 0.f);
#pragma unroll
      for (int jj = 0; jj < 4; jj++) {
        const float4 wa = *(const float4*)&Wl[(k + jj) * COLS + c0];
        const float4 wb = *(const float4*)&Wl[(k + jj) * COLS + c0 + 4];
#pragma unroll
        for (int i = 0; i < ROWS; i++) {
          float xs = f4get(xv[i], jj);
          acc[i][0] = fmaf(xs, wa.x, acc[i][0]);
          acc[i][1] = fmaf(xs, wa.y, acc[i][1]);
          acc[i][2] = fmaf(xs, wa.z, acc[i][2]);
          acc[i][3] = fmaf(xs, wa.w, acc[i][3]);
          acc[i][4] = fmaf(xs, wb.x, acc[i][4]);
          acc[i][5] = fmaf(xs, wb.y, acc[i][5]);
          acc[i][6] = fmaf(xs, wb.z, acc[i][6]);
          acc[i][7] = fmaf(xs, wb.w, acc[i][7]);
        }
      }
    }
  }

  float bo[8];
  if (BIAS) {
#pragma unroll
    for (int c = 0; c < 8; c++) bo[c] = bias[c0 + c];
  }
  float m = -3.4e38f;
#pragma unroll
  for (int i = 0; i < ROWS; i++) {
    if (!rv[i]) continue;
    float dv = SCALE ? dinv[r0 + i] : 1.f;
    float o[8];
#pragma unroll
    for (int c = 0; c < 8; c++) {
      float v = acc[i][c];
      if (BIAS) v += bo[c];
      if (SCALE) v *= dv;
      if (RELU) v = fmaxf(v, 0.f);
      if (DOMAX) m = fmaxf(m, v);
      o[c] = v;
    }
    float* op = &out[(r0 + i) * COLS + c0];
    *(float4*)(op) = make_float4(o[0], o[1], o[2], o[3]);
    *(float4*)(op + 4) = make_float4(o[4], o[5], o[6], o[7]);
  }
  if constexpr (DOMAX) {
    __shared__ float red[BT];
    red[threadIdx.x] = m;
    __syncthreads();
    for (int o = BT / 2; o > 0; o >>= 1) {
      if (threadIdx.x < o) red[threadIdx.x] = fmaxf(red[threadIdx.x], red[threadIdx.x + o]);
      __syncthreads();
    }
    if (threadIdx.x == 0) atomicMax(gmax, fkey(red[0]));
  }
}

// ---------- GCN aggregation (float4 lanes) ----------
template <int FEAT, bool BIAS, bool RELU, bool PSCALE>
__launch_bounds__(256)
__global__ void k_aggv(const float* __restrict__ g, const int* __restrict__ col,
                       const int* __restrict__ rowptr, const int* __restrict__ deg,
                       const float* __restrict__ dinv, const float* __restrict__ bias,
                       float* __restrict__ out, int N) {
  constexpr int LPN = FEAT / 4;       // lanes per node (float4 each)
  constexpr int NPB = 256 / LPN;      // nodes per block
  int nib = threadIdx.x / LPN;
  int c = threadIdx.x % LPN;
  long v = (long)blockIdx.x * NPB + nib;
  if (v >= N) return;

  const float4* g4 = (const float4*)g;
  float4 acc = g4[v * LPN + c];       // self-loop term
  int start = rowptr[v], dg = deg[v];
  int e = 0;
  while (e < dg) {
    int cnt = min(LPN, dg - e);
    int idx = (c < cnt) ? col[start + e + c] : 0;
    int j = 0;
    for (; j + 4 <= cnt; j += 4) {    // 4 independent 16B gathers in flight
      int u0 = __shfl(idx, j + 0, LPN);
      int u1 = __shfl(idx, j + 1, LPN);
      int u2 = __shfl(idx, j + 2, LPN);
      int u3 = __shfl(idx, j + 3, LPN);
      float4 a0 = g4[(long)u0 * LPN + c];
      float4 a1 = g4[(long)u1 * LPN + c];
      float4 a2 = g4[(long)u2 * LPN + c];
      float4 a3 = g4[(long)u3 * LPN + c];
      acc.x += (a0.x + a1.x) + (a2.x + a3.x);
      acc.y += (a0.y + a1.y) + (a2.y + a3.y);
      acc.z += (a0.z + a1.z) + (a2.z + a3.z);
      acc.w += (a0.w + a1.w) + (a2.w + a3.w);
    }
    for (; j < cnt; j++) {
      int u = __shfl(idx, j, LPN);
      float4 a = g4[(long)u * LPN + c];
      acc.x += a.x; acc.y += a.y; acc.z += a.z; acc.w += a.w;
    }
    e += cnt;
  }
  float dv = dinv[v];
  float4 val;
  val.x = acc.x * dv; val.y = acc.y * dv; val.z = acc.z * dv; val.w = acc.w * dv;
  if (BIAS) {
    float4 b = ((const float4*)bias)[c];
    val.x += b.x; val.y += b.y; val.z += b.z; val.w += b.w;
  }
  if (RELU) {
    val.x = fmaxf(val.x, 0.f); val.y = fmaxf(val.y, 0.f);
    val.z = fmaxf(val.z, 0.f); val.w = fmaxf(val.w, 0.f);
  }
  if (PSCALE) {
    val.x *= dv; val.y *= dv; val.z *= dv; val.w *= dv;
  }
  ((float4*)out)[v * LPN + c] = val;
}

// ---------- softmax ----------
__global__ void k_smsum(const float* __restrict__ logit, unsigned* __restrict__ scal, int total) {
  __shared__ float s[256];
  float gmax = funkey(scal[0]);
  float loc = 0.f;
  for (int i = blockIdx.x * 256 + threadIdx.x; i < total; i += gridDim.x * 256)
    loc += expf(logit[i] - gmax);
  s[threadIdx.x] = loc; __syncthreads();
  for (int o = 128; o > 0; o >>= 1) {
    if (threadIdx.x < o) s[threadIdx.x] += s[threadIdx.x + o];
    __syncthreads();
  }
  if (threadIdx.x == 0) atomicAdd((float*)&scal[1], s[0]);
}

__global__ void k_smnorm(float* __restrict__ logit, const unsigned* __restrict__ scal, int total) {
  float gmax = funkey(scal[0]);
  float inv = 1.0f / __uint_as_float(scal[1]);
  int i = blockIdx.x * 256 + threadIdx.x;
  if (i < total) logit[i] = expf(logit[i] - gmax) * inv;
}

// ---------- launch ----------
extern "C" void kernel_launch(void* const* d_in, const int* in_sizes, int n_in,
                              void* d_out, int out_size, void* d_ws, size_t ws_size,
                              hipStream_t stream) {
  const float* x   = (const float*)d_in[0];
  const int*   ei  = (const int*)d_in[1];
  const float* W1  = (const float*)d_in[3];
  const float* b1  = (const float*)d_in[4];
  const float* W2  = (const float*)d_in[5];
  const float* b2  = (const float*)d_in[6];
  const float* Wo1 = (const float*)d_in[7];
  const float* bo1 = (const float*)d_in[8];
  const float* Wo2 = (const float*)d_in[9];
  const float* bo2 = (const float*)d_in[10];

  const int N = in_sizes[0] / 256;   // in_dim = 256
  const int E = in_sizes[1] / 2;
  const int* src = ei;
  const int* dst = ei + E;
  const int NB = (N + BNODES - 1) / BNODES;

  size_t o = 0;
  auto carve = [&](size_t bytes) -> char* {
    char* p = (char*)d_ws + o;
    o += (bytes + 255) & ~(size_t)255;
    return p;
  };
  float* R1     = (float*)carve((size_t)N * 64 * 4);  // g1 | s2 | t
  float* R2     = (float*)carve((size_t)N * 64 * 4);  // epart | p | z2
  int*   col    = (int*)carve((size_t)E * 4);
  int*   deg    = (int*)carve((size_t)N * 4);
  float* dinv   = (float*)carve((size_t)N * 4);
  int*   rowptr = (int*)carve((size_t)N * 4);
  int*   bcnt   = (int*)carve(256 * 4);
  int*   bbase  = (int*)carve(256 * 4);
  int*   bcur   = (int*)carve(256 * 4);
  unsigned* scal = (unsigned*)carve(64);

  unsigned* epart = (unsigned*)R2;  // dead before p is written
  float* g1 = R1;   // N x 32
  float* p  = R2;   // N x 32: dinv .* relu(layer-1 out)
  float* s2 = R1;   // N x 32: aggregated p (g1 dead)
  float* z2 = R2;   // N x 64: relu(s2@W2+b2) (p dead)
  float* t  = R1;   // N x 64: relu(z2@Wo1+bo1) (s2 dead)
  float* logits = (float*)d_out;

  // ---- CSR build ----
  k_binit<<<1, 256, 0, stream>>>(bcnt);
  k_bcount<<<512, 256, 0, stream>>>(dst, bcnt, E, NB);
  k_bscan<<<1, 256, 0, stream>>>(bcnt, bbase, bcur, scal, NB);
  k_bpart<<<(E + PCHUNK - 1) / PCHUNK, 256, 0, stream>>>(src, dst, bcur, epart, E, NB);
  k_fine<<<NB, 256, 0, stream>>>(epart, bbase, bcnt, rowptr, deg, dinv, col, N);

  const int gG = (N + 127) / 128;   // all gemms: 128 rows per block
  const int gA = (N + 31) / 32;     // agg32: 32 nodes per block

  // layer 1: g1 = dinv .* (x @ W1); p = dinv .* relu(b1 + dinv*(g1[v]+sum g1[u]))
  k_gemm<256, 128, 32, 128, 4, false, false, true, false>
      <<<gG, 128, 0, stream>>>(x, W1, nullptr, dinv, g1, N, nullptr);
  k_aggv<32, true, true, true><<<gA, 256, 0, stream>>>(g1, col, rowptr, deg, dinv, b1, p, N);

  // layer 2 (aggregation commuted before W2): s2 = dinv*(p[v]+sum p[u]); z2 = relu(s2@W2+b2)
  k_aggv<32, false, false, false><<<gA, 256, 0, stream>>>(p, col, rowptr, deg, dinv, nullptr, s2, N);
  k_gemm<32, 32, 64, 256, 4, true, true, false, false>
      <<<gG, 256, 0, stream>>>(s2, W2, b2, nullptr, z2, N, nullptr);

  // MLP head
  k_gemm<64, 64, 64, 256, 4, true, true, false, false>
      <<<gG, 256, 0, stream>>>(z2, Wo1, bo1, nullptr, t, N, nullptr);
  k_gemm<64, 64, 64, 256, 4, true, false, false, true>
      <<<gG, 256, 0, stream>>>(t, Wo2, bo2, nullptr, logits, N, scal);

  // softmax over all N*64 logits
  k_smsum<<<1024, 256, 0, stream>>>(logits, scal, out_size);
  k_smnorm<<<(out_size + 255) / 256, 256, 0, stream>>>(logits, scal, out_size);
}

// Round 7
// 537.635 us; speedup vs baseline: 1.0815x; 1.0815x over previous
//
#include <hip/hip_runtime.h>

#define DEVI __device__ __forceinline__

// ---------- helpers ----------
DEVI unsigned fkey(float f) {             // order-preserving float->uint key
  unsigned u = __float_as_uint(f);
  return u ^ ((u >> 31) ? 0xFFFFFFFFu : 0x80000000u);
}
DEVI float funkey(unsigned k) {
  unsigned b = (k & 0x80000000u) ? (k ^ 0x80000000u) : ~k;
  return __uint_as_float(b);
}
DEVI float f4get(const float4& v, int j) {
  return j == 0 ? v.x : j == 1 ? v.y : j == 2 ? v.z : v.w;
}

// ================= CSR build: bucketed counting sort by dst =================
constexpr int BSH = 9;                 // 512 nodes per bucket
constexpr int BNODES = 1 << BSH;
constexpr int PEPT = 16;               // partition: edges per thread
constexpr int PCHUNK = 256 * PEPT;     // 4096 edges per block

__global__ void k_binit(int* __restrict__ bcnt) {
  bcnt[threadIdx.x] = 0;
}

__global__ void k_bcount(const int* __restrict__ dst, int* __restrict__ bcnt,
                         int E, int NB) {
  __shared__ int lh[256];
  lh[threadIdx.x] = 0;
  __syncthreads();
  int stride = gridDim.x * 256;
  for (long i = (long)blockIdx.x * 256 + threadIdx.x; i < E; i += stride)
    atomicAdd(&lh[dst[i] >> BSH], 1);
  __syncthreads();
  if (threadIdx.x < NB && lh[threadIdx.x]) atomicAdd(&bcnt[threadIdx.x], lh[threadIdx.x]);
}

__global__ void k_bscan(const int* __restrict__ bcnt, int* __restrict__ bbase,
                        int* __restrict__ bcur, unsigned* __restrict__ scal, int NB) {
  __shared__ int s[256];
  int t = threadIdx.x;
  int v = (t < NB) ? bcnt[t] : 0;
  s[t] = v;
  __syncthreads();
  for (int o = 1; o < 256; o <<= 1) {
    int add = (t >= o) ? s[t - o] : 0;
    __syncthreads();
    s[t] += add;
    __syncthreads();
  }
  int excl = s[t] - v;
  if (t < NB) { bbase[t] = excl; bcur[t] = excl; }
  if (t == 0) { scal[0] = 0u; scal[1] = 0u; }
}

// pack = (dst&511)<<17 | src  (requires N <= 2^17)
__global__ __launch_bounds__(256)
void k_bpart(const int* __restrict__ src, const int* __restrict__ dst,
             int* __restrict__ bcur, unsigned* __restrict__ epart, int E, int NB) {
  __shared__ int lh[256];
  __shared__ int gbase[256];
  long base = (long)blockIdx.x * PCHUNK;
  lh[threadIdx.x] = 0;
  __syncthreads();
  int ed[PEPT]; int es[PEPT]; unsigned short lpos[PEPT];
#pragma unroll
  for (int j = 0; j < PEPT; j++) {
    long i = base + threadIdx.x + (long)j * 256;   // coalesced
    if (i < E) {
      int d = dst[i];
      es[j] = src[i];
      ed[j] = d;
      lpos[j] = (unsigned short)atomicAdd(&lh[d >> BSH], 1);
    } else {
      ed[j] = -1;
    }
  }
  __syncthreads();
  if (threadIdx.x < NB) {
    int c = lh[threadIdx.x];
    gbase[threadIdx.x] = c ? atomicAdd(&bcur[threadIdx.x], c) : 0;
  }
  __syncthreads();
#pragma unroll
  for (int j = 0; j < PEPT; j++) {
    int d = ed[j];
    if (d >= 0) {
      unsigned p = (unsigned)(gbase[d >> BSH] + (int)lpos[j]);
      epart[p] = ((unsigned)(d & (BNODES - 1)) << 17) | (unsigned)es[j];
    }
  }
}

// one block per bucket: per-node hist + scan -> deg/rowptr/dinv, scatter col
__global__ __launch_bounds__(256)
void k_fine(const unsigned* __restrict__ epart, const int* __restrict__ bbase,
            const int* __restrict__ bcnt, int* __restrict__ rowptr,
            int* __restrict__ deg, float* __restrict__ dinv,
            int* __restrict__ col, int N) {
  __shared__ int lh[BNODES];
  __shared__ int lexcl[BNODES];
  __shared__ int ssc[256];
  int b = blockIdx.x;
  int base = bbase[b], cnt = bcnt[b];
  int nlo = b << BSH;
  int t = threadIdx.x;
  lh[t] = 0; lh[t + 256] = 0;
  __syncthreads();
  for (int i = t; i < cnt; i += 256) {
    unsigned e = epart[base + i];
    atomicAdd(&lh[e >> 17], 1);
  }
  __syncthreads();
  int a0 = lh[2 * t], a1 = lh[2 * t + 1];
  ssc[t] = a0 + a1;
  __syncthreads();
  for (int o = 1; o < 256; o <<= 1) {
    int add = (t >= o) ? ssc[t - o] : 0;
    __syncthreads();
    ssc[t] += add;
    __syncthreads();
  }
  int excl = ssc[t] - (a0 + a1);
  lexcl[2 * t] = excl;
  lexcl[2 * t + 1] = excl + a0;
  __syncthreads();
#pragma unroll
  for (int k = 0; k < 2; k++) {
    int i = t + k * 256;
    int v = nlo + i;
    if (v < N) {
      int dgv = lh[i];
      deg[v] = dgv;
      rowptr[v] = base + lexcl[i];
      dinv[v] = rsqrtf((float)(dgv + 1));
    }
  }
  __syncthreads();
  lh[2 * t] = lexcl[2 * t];
  lh[2 * t + 1] = lexcl[2 * t + 1];
  __syncthreads();
  for (int i = t; i < cnt; i += 256) {
    unsigned e = epart[base + i];
    int p = atomicAdd(&lh[e >> 17], 1);
    col[base + p] = (int)(e & 0x1FFFFu);
  }
}

// ---------- gemm1: x[Nx256] @ W1[256x32], split-K x2, scaled by dinv ----------
// Latency-bound kernel (R4: 83 us at 31% occ). 512 threads: waves 0-3 do
// K=[0,128), waves 4-7 do K=[128,256) for the SAME 64 rows; upper half dumps
// partials to LDS, lower half combines + scales + stores. 12.5k waves total,
// LDS 40 KB -> 4 blocks/CU = 32 waves/CU (wave cap). unroll 2 (R3: full
// unroll hoisted loads -> 256 VGPR -> scratch spill).
__global__ __launch_bounds__(512)
void k_gemm1(const float* __restrict__ in, const float* __restrict__ W,
             const float* __restrict__ dinv, float* __restrict__ out, int N) {
  __shared__ float Wl[256 * 32];      // 32 KB
  __shared__ float red[256 * 8];      // 8 KB
  int t = threadIdx.x;
  int kh = t >> 8;                    // K-half: 0 or 1
  int tl = t & 255;
  int cg = tl & 3, rg = tl >> 2;
  int c0 = cg * 8;
  long r0 = (long)blockIdx.x * 64 + rg;
  bool rv = r0 < (long)N;

  for (int i = t; i < 256 * 32; i += 512) Wl[i] = W[i];
  __syncthreads();

  const float* ip = in + r0 * 256 + kh * 128;
  const float* wp = &Wl[kh * 128 * 32];

  float acc[8];
#pragma unroll
  for (int c = 0; c < 8; c++) acc[c] = 0.f;

#pragma unroll 2
  for (int k = 0; k < 128; k += 4) {
    float4 xv = rv ? *(const float4*)(ip + k) : make_float4(0.f, 0.f, 0.f, 0.f);
#pragma unroll
    for (int jj = 0; jj < 4; jj++) {
      const float4 wa = *(const float4*)&wp[(k + jj) * 32 + c0];
      const float4 wb = *(const float4*)&wp[(k + jj) * 32 + c0 + 4];
      float xs = f4get(xv, jj);
      acc[0] = fmaf(xs, wa.x, acc[0]);
      acc[1] = fmaf(xs, wa.y, acc[1]);
      acc[2] = fmaf(xs, wa.z, acc[2]);
      acc[3] = fmaf(xs, wa.w, acc[3]);
      acc[4] = fmaf(xs, wb.x, acc[4]);
      acc[5] = fmaf(xs, wb.y, acc[5]);
      acc[6] = fmaf(xs, wb.z, acc[6]);
      acc[7] = fmaf(xs, wb.w, acc[7]);
    }
  }

  if (kh) {
    float* rp = &red[tl * 8];
    *(float4*)(rp) = make_float4(acc[0], acc[1], acc[2], acc[3]);
    *(float4*)(rp + 4) = make_float4(acc[4], acc[5], acc[6], acc[7]);
  }
  __syncthreads();
  if (!kh && rv) {
    const float* rp = &red[tl * 8];
    float4 ha = *(const float4*)(rp);
    float4 hb = *(const float4*)(rp + 4);
    float dv = dinv[r0];
    float* op = &out[r0 * 32 + c0];
    *(float4*)(op) = make_float4((acc[0] + ha.x) * dv, (acc[1] + ha.y) * dv,
                                 (acc[2] + ha.z) * dv, (acc[3] + ha.w) * dv);
    *(float4*)(op + 4) = make_float4((acc[4] + hb.x) * dv, (acc[5] + hb.y) * dv,
                                     (acc[6] + hb.z) * dv, (acc[7] + hb.w) * dv);
  }
}

// ---------- tall-skinny fp32 GEMM: out = post(in[NxK] @ W[KxCOLS]) ----------
// ROWS rows x 8 cols per thread; W in LDS. k-loop unroll capped at 2 (R3:
// full unroll hoisted all loads -> 256 VGPR -> scratch spill, 500 MB HBM).
template <int K, int COLS, int ROWS, bool BIAS, bool RELU, bool SCALE, bool DOMAX>
__launch_bounds__(256)
__global__ void k_gemm(const float* __restrict__ in, const float* __restrict__ W,
                       const float* __restrict__ bias, const float* __restrict__ dinv,
                       float* __restrict__ out, int N, unsigned* __restrict__ gmax) {
  constexpr int CG = COLS / 8;        // col-groups of 8
  constexpr int RG = 256 / CG;        // row-groups
  constexpr int RPB = RG * ROWS;      // rows per block
  __shared__ float Wl[K * COLS];
  for (int i = threadIdx.x; i < K * COLS; i += 256) Wl[i] = W[i];
  __syncthreads();

  int cg = threadIdx.x % CG, rg = threadIdx.x / CG;
  int c0 = cg * 8;
  long r0 = (long)blockIdx.x * RPB + rg * ROWS;

  float acc[ROWS][8];
#pragma unroll
  for (int i = 0; i < ROWS; i++)
#pragma unroll
    for (int c = 0; c < 8; c++) acc[i][c] = 0.f;
  bool rv[ROWS];
#pragma unroll
  for (int i = 0; i < ROWS; i++) rv[i] = (r0 + i) < (long)N;

  const float* ip = in + r0 * K;
#pragma unroll 2
  for (int k = 0; k < K; k += 4) {
    float4 xv[ROWS];
#pragma unroll
    for (int i = 0; i < ROWS; i++)
      xv[i] = rv[i] ? *(const float4*)(ip + (long)i * K + k) : make_float4(0.f, 0.f, 0.f, 0.f);
#pragma unroll
    for (int jj = 0; jj < 4; jj++) {
      const float4 wa = *(const float4*)&Wl[(k + jj) * COLS + c0];
      const float4 wb = *(const float4*)&Wl[(k + jj) * COLS + c0 + 4];
#pragma unroll
      for (int i = 0; i < ROWS; i++) {
        float xs = f4get(xv[i], jj);
        acc[i][0] = fmaf(xs, wa.x, acc[i][0]);
        acc[i][1] = fmaf(xs, wa.y, acc[i][1]);
        acc[i][2] = fmaf(xs, wa.z, acc[i][2]);
        acc[i][3] = fmaf(xs, wa.w, acc[i][3]);
        acc[i][4] = fmaf(xs, wb.x, acc[i][4]);
        acc[i][5] = fmaf(xs, wb.y, acc[i][5]);
        acc[i][6] = fmaf(xs, wb.z, acc[i][6]);
        acc[i][7] = fmaf(xs, wb.w, acc[i][7]);
      }
    }
  }

  float bo[8];
  if (BIAS) {
#pragma unroll
    for (int c = 0; c < 8; c++) bo[c] = bias[c0 + c];
  }
  float m = -3.4e38f;
#pragma unroll
  for (int i = 0; i < ROWS; i++) {
    if (!rv[i]) continue;
    float dv = SCALE ? dinv[r0 + i] : 1.f;
    float o[8];
#pragma unroll
    for (int c = 0; c < 8; c++) {
      float v = acc[i][c];
      if (BIAS) v += bo[c];
      if (SCALE) v *= dv;
      if (RELU) v = fmaxf(v, 0.f);
      if (DOMAX) m = fmaxf(m, v);
      o[c] = v;
    }
    float* op = &out[(r0 + i) * COLS + c0];
    *(float4*)(op) = make_float4(o[0], o[1], o[2], o[3]);
    *(float4*)(op + 4) = make_float4(o[4], o[5], o[6], o[7]);
  }
  if constexpr (DOMAX) {
    __shared__ float red[256];
    red[threadIdx.x] = m;
    __syncthreads();
    for (int o = 128; o > 0; o >>= 1) {
      if (threadIdx.x < o) red[threadIdx.x] = fmaxf(red[threadIdx.x], red[threadIdx.x + o]);
      __syncthreads();
    }
    if (threadIdx.x == 0) atomicMax(gmax, fkey(red[0]));
  }
}

// ---------- GCN aggregation (float4 lanes) ----------
template <int FEAT, bool BIAS, bool RELU, bool PSCALE>
__launch_bounds__(256)
__global__ void k_aggv(const float* __restrict__ g, const int* __restrict__ col,
                       const int* __restrict__ rowptr, const int* __restrict__ deg,
                       const float* __restrict__ dinv, const float* __restrict__ bias,
                       float* __restrict__ out, int N) {
  constexpr int LPN = FEAT / 4;       // lanes per node (float4 each)
  constexpr int NPB = 256 / LPN;      // nodes per block
  int nib = threadIdx.x / LPN;
  int c = threadIdx.x % LPN;
  long v = (long)blockIdx.x * NPB + nib;
  if (v >= N) return;

  const float4* g4 = (const float4*)g;
  float4 acc = g4[v * LPN + c];       // self-loop term
  int start = rowptr[v], dg = deg[v];
  int e = 0;
  while (e < dg) {
    int cnt = min(LPN, dg - e);
    int idx = (c < cnt) ? col[start + e + c] : 0;
    int j = 0;
    for (; j + 4 <= cnt; j += 4) {    // 4 independent 16B gathers in flight
      int u0 = __shfl(idx, j + 0, LPN);
      int u1 = __shfl(idx, j + 1, LPN);
      int u2 = __shfl(idx, j + 2, LPN);
      int u3 = __shfl(idx, j + 3, LPN);
      float4 a0 = g4[(long)u0 * LPN + c];
      float4 a1 = g4[(long)u1 * LPN + c];
      float4 a2 = g4[(long)u2 * LPN + c];
      float4 a3 = g4[(long)u3 * LPN + c];
      acc.x += (a0.x + a1.x) + (a2.x + a3.x);
      acc.y += (a0.y + a1.y) + (a2.y + a3.y);
      acc.z += (a0.z + a1.z) + (a2.z + a3.z);
      acc.w += (a0.w + a1.w) + (a2.w + a3.w);
    }
    for (; j < cnt; j++) {
      int u = __shfl(idx, j, LPN);
      float4 a = g4[(long)u * LPN + c];
      acc.x += a.x; acc.y += a.y; acc.z += a.z; acc.w += a.w;
    }
    e += cnt;
  }
  float dv = dinv[v];
  float4 val;
  val.x = acc.x * dv; val.y = acc.y * dv; val.z = acc.z * dv; val.w = acc.w * dv;
  if (BIAS) {
    float4 b = ((const float4*)bias)[c];
    val.x += b.x; val.y += b.y; val.z += b.z; val.w += b.w;
  }
  if (RELU) {
    val.x = fmaxf(val.x, 0.f); val.y = fmaxf(val.y, 0.f);
    val.z = fmaxf(val.z, 0.f); val.w = fmaxf(val.w, 0.f);
  }
  if (PSCALE) {
    val.x *= dv; val.y *= dv; val.z *= dv; val.w *= dv;
  }
  ((float4*)out)[v * LPN + c] = val;
}

// ---------- softmax ----------
__global__ void k_smsum(const float* __restrict__ logit, unsigned* __restrict__ scal, int total) {
  __shared__ float s[256];
  float gmax = funkey(scal[0]);
  float loc = 0.f;
  for (int i = blockIdx.x * 256 + threadIdx.x; i < total; i += gridDim.x * 256)
    loc += expf(logit[i] - gmax);
  s[threadIdx.x] = loc; __syncthreads();
  for (int o = 128; o > 0; o >>= 1) {
    if (threadIdx.x < o) s[threadIdx.x] += s[threadIdx.x + o];
    __syncthreads();
  }
  if (threadIdx.x == 0) atomicAdd((float*)&scal[1], s[0]);
}

__global__ void k_smnorm(float* __restrict__ logit, const unsigned* __restrict__ scal, int total) {
  float gmax = funkey(scal[0]);
  float inv = 1.0f / __uint_as_float(scal[1]);
  int i = blockIdx.x * 256 + threadIdx.x;
  if (i < total) logit[i] = expf(logit[i] - gmax) * inv;
}

// ---------- launch ----------
extern "C" void kernel_launch(void* const* d_in, const int* in_sizes, int n_in,
                              void* d_out, int out_size, void* d_ws, size_t ws_size,
                              hipStream_t stream) {
  const float* x   = (const float*)d_in[0];
  const int*   ei  = (const int*)d_in[1];
  const float* W1  = (const float*)d_in[3];
  const float* b1  = (const float*)d_in[4];
  const float* W2  = (const float*)d_in[5];
  const float* b2  = (const float*)d_in[6];
  const float* Wo1 = (const float*)d_in[7];
  const float* bo1 = (const float*)d_in[8];
  const float* Wo2 = (const float*)d_in[9];
  const float* bo2 = (const float*)d_in[10];

  const int N = in_sizes[0] / 256;   // in_dim = 256
  const int E = in_sizes[1] / 2;
  const int* src = ei;
  const int* dst = ei + E;
  const int NB = (N + BNODES - 1) / BNODES;

  size_t o = 0;
  auto carve = [&](size_t bytes) -> char* {
    char* p = (char*)d_ws + o;
    o += (bytes + 255) & ~(size_t)255;
    return p;
  };
  float* R1     = (float*)carve((size_t)N * 64 * 4);  // g1 | s2 | t
  float* R2     = (float*)carve((size_t)N * 64 * 4);  // epart | p | z2
  int*   col    = (int*)carve((size_t)E * 4);
  int*   deg    = (int*)carve((size_t)N * 4);
  float* dinv   = (float*)carve((size_t)N * 4);
  int*   rowptr = (int*)carve((size_t)N * 4);
  int*   bcnt   = (int*)carve(256 * 4);
  int*   bbase  = (int*)carve(256 * 4);
  int*   bcur   = (int*)carve(256 * 4);
  unsigned* scal = (unsigned*)carve(64);

  unsigned* epart = (unsigned*)R2;  // dead before p is written
  float* g1 = R1;   // N x 32
  float* p  = R2;   // N x 32: dinv .* relu(layer-1 out)
  float* s2 = R1;   // N x 32: aggregated p (g1 dead)
  float* z2 = R2;   // N x 64: relu(s2@W2+b2) (p dead)
  float* t  = R1;   // N x 64: relu(z2@Wo1+bo1) (s2 dead)
  float* logits = (float*)d_out;

  // ---- CSR build ----
  k_binit<<<1, 256, 0, stream>>>(bcnt);
  k_bcount<<<512, 256, 0, stream>>>(dst, bcnt, E, NB);
  k_bscan<<<1, 256, 0, stream>>>(bcnt, bbase, bcur, scal, NB);
  k_bpart<<<(E + PCHUNK - 1) / PCHUNK, 256, 0, stream>>>(src, dst, bcur, epart, E, NB);
  k_fine<<<NB, 256, 0, stream>>>(epart, bbase, bcnt, rowptr, deg, dinv, col, N);

  const int gG = (N + 63) / 64;     // 64 rows per block
  const int gA = (N + 31) / 32;     // agg32: 32 nodes per block

  // layer 1: g1 = dinv .* (x @ W1); p = dinv .* relu(b1 + dinv*(g1[v]+sum g1[u]))
  k_gemm1<<<gG, 512, 0, stream>>>(x, W1, dinv, g1, N);
  k_aggv<32, true, true, true><<<gA, 256, 0, stream>>>(g1, col, rowptr, deg, dinv, b1, p, N);

  // layer 2 (aggregation commuted before W2): s2 = dinv*(p[v]+sum p[u]); z2 = relu(s2@W2+b2)
  k_aggv<32, false, false, false><<<gA, 256, 0, stream>>>(p, col, rowptr, deg, dinv, nullptr, s2, N);
  k_gemm<32, 64, 2, true, true, false, false>
      <<<gG, 256, 0, stream>>>(s2, W2, b2, nullptr, z2, N, nullptr);

  // MLP head
  k_gemm<64, 64, 2, true, true, false, false>
      <<<gG, 256, 0, stream>>>(z2, Wo1, bo1, nullptr, t, N, nullptr);
  k_gemm<64, 64, 2, true, false, false, true>
      <<<gG, 256, 0, stream>>>(t, Wo2, bo2, nullptr, logits, N, scal);

  // softmax over all N*64 logits
  k_smsum<<<1024, 256, 0, stream>>>(logits, scal, out_size);
  k_smnorm<<<(out_size + 255) / 256, 256, 0, stream>>>(logits, scal, out_size);
}